// Round 13
// baseline (184.595 us; speedup 1.0000x reference)
//
#include <hip/hip_runtime.h>

// Chamfer via MFMA (math verified exact in R11/R12): d[n,m] = na + nb - 2 a.b
// as ONE bf16 MFMA (16x16x32) per 16x16 tile, 13-slot K packing w/ hi/lo:
//   k 0-2: ah*(-2bh)  k 3-5: ah*(-2bl)  k 6-8: al*(-2bh)
//   k 9,10: nah,nal * 1   k 11,12: 1 * nbh,nbl   k>=13: zero (g>=2 lanes)
// Each matrix computed ONCE: row-mins -> d1/p1, col-mins -> d2/p2.
// R13 schedule: NO cross-lane ops in the t-loop. Per-lane col partials in
// a fully-unrolled register array colm[16] (2 halves); batched shfl_xor +
// one atomicMin per col at half boundaries. Row mins as before. LDS = sB
// only (24 KB). atomicMin monotone-key table (exact, order-independent ->
// deterministic); min-table 0xFF init fused into prep.

#define N2K 2048
#define N8K 8192
#define THREADS 256

// ws u32 layout:
#define D1_BASE 0          // d1: b*8192+a
#define D2_BASE 65536      // d2: b*2048+a
#define P1_BASE 81920      // p1: b*8192+p*2048+a
#define P2_BASE 147456     // p2: b*8192+p*2048+a
#define NMINS 212992
#define PART_BASE 212992   // 208 floats
#define RV_BASE 213504     // data row-vecs : 65536 pts x 8 u32 (32B)
#define CR_BASE 737792     // rec  col-vecs : 16384 pts x 8 u32
#define CP_BASE 868864     // recp col-vecs : 65536 pts x 8 u32  (end 1393152)

typedef short bf16x8 __attribute__((ext_vector_type(8)));
typedef float f32x4 __attribute__((ext_vector_type(4)));

__device__ __forceinline__ float min3f(float a, float b, float c) {
    float d;
    asm("v_min3_f32 %0, %1, %2, %3" : "=v"(d) : "v"(a), "v"(b), "v"(c));
    return d;
}
__device__ __forceinline__ unsigned int fkey(float v) {
    unsigned int u = __float_as_uint(v);
    return (u & 0x80000000u) ? ~u : (u | 0x80000000u);
}
__device__ __forceinline__ unsigned short bf16rne(float f) {
    unsigned int u = __float_as_uint(f);
    return (unsigned short)((u + 0x7FFFu + ((u >> 16) & 1u)) >> 16);
}
__device__ __forceinline__ float bf2f(unsigned short s) {
    return __uint_as_float(((unsigned int)s) << 16);
}

__global__ __launch_bounds__(THREADS) void prep_kernel(
    const float* __restrict__ data, const float* __restrict__ rec,
    const float* __restrict__ recp, unsigned int* __restrict__ ws)
{
    const int idx = blockIdx.x * THREADS + threadIdx.x;   // 0..147455

    // fused min-table init (replaces hipMemsetAsync): [0, NMINS) <- 0xFF..
    if (idx < NMINS) ws[idx] = 0xFFFFFFFFu;
    if (idx + 147456 < NMINS) ws[idx + 147456] = 0xFFFFFFFFu;

    float x, y, z; int out; int isrow;
    if (idx < 65536) {                       // data -> row vectors
        int b = idx >> 13, i = idx & 8191;
        const float* p = data + b * 3 * N8K;
        x = p[i]; y = p[N8K + i]; z = p[2 * N8K + i];
        out = RV_BASE + idx * 8; isrow = 1;
    } else if (idx < 81920) {                // rec -> col vectors
        int j = idx - 65536; int b = j >> 11, i = j & 2047;
        const float* p = rec + b * 3 * N2K;
        x = p[i]; y = p[N2K + i]; z = p[2 * N2K + i];
        out = CR_BASE + j * 8; isrow = 0;
    } else {                                 // recp -> col vectors
        int j = idx - 81920; int b = j >> 13, i = j & 8191;
        const float* p = recp + b * 3 * N8K;
        x = p[i]; y = p[N8K + i]; z = p[2 * N8K + i];
        out = CP_BASE + j * 8; isrow = 0;
    }
    unsigned short xh = bf16rne(x), yh = bf16rne(y), zh = bf16rne(z);
    unsigned short xl = bf16rne(x - bf2f(xh));
    unsigned short yl = bf16rne(y - bf2f(yh));
    unsigned short zl = bf16rne(z - bf2f(zh));
    float na = x * x + y * y + z * z;
    unsigned short nh = bf16rne(na);
    unsigned short nl = bf16rne(na - bf2f(nh));
    const unsigned short ONE = 0x3F80u;
    unsigned short s[16];
    if (isrow) {
        s[0]=xh; s[1]=yh; s[2]=zh;  s[3]=xh; s[4]=yh; s[5]=zh;
        s[6]=xl; s[7]=yl; s[8]=zl;  s[9]=nh; s[10]=nl;
        s[11]=ONE; s[12]=ONE; s[13]=0; s[14]=0; s[15]=0;
    } else {
        unsigned short m2xh = bf16rne(-2.f * bf2f(xh));
        unsigned short m2yh = bf16rne(-2.f * bf2f(yh));
        unsigned short m2zh = bf16rne(-2.f * bf2f(zh));
        unsigned short m2xl = bf16rne(-2.f * bf2f(xl));
        unsigned short m2yl = bf16rne(-2.f * bf2f(yl));
        unsigned short m2zl = bf16rne(-2.f * bf2f(zl));
        s[0]=m2xh; s[1]=m2yh; s[2]=m2zh;  s[3]=m2xl; s[4]=m2yl; s[5]=m2zl;
        s[6]=m2xh; s[7]=m2yh; s[8]=m2zh;  s[9]=ONE; s[10]=ONE;
        s[11]=nh; s[12]=nl; s[13]=0; s[14]=0; s[15]=0;
    }
    uint4 w0, w1;
    w0.x = (unsigned)s[0]  | ((unsigned)s[1]  << 16);
    w0.y = (unsigned)s[2]  | ((unsigned)s[3]  << 16);
    w0.z = (unsigned)s[4]  | ((unsigned)s[5]  << 16);
    w0.w = (unsigned)s[6]  | ((unsigned)s[7]  << 16);
    w1.x = (unsigned)s[8]  | ((unsigned)s[9]  << 16);
    w1.y = (unsigned)s[10] | ((unsigned)s[11] << 16);
    w1.z = (unsigned)s[12] | ((unsigned)s[13] << 16);
    w1.w = (unsigned)s[14] | ((unsigned)s[15] << 16);
    uint4* dst = (uint4*)(ws + out);
    dst[0] = w0; dst[1] = w1;
}

__global__ __launch_bounds__(THREADS) void mfma_chamfer_kernel(unsigned int* ws)
{
    __shared__ unsigned int sB[512 * 12];   // col-vecs, 48B stride (24 KB)

    const int tid = threadIdx.x, lane = tid & 63, wv = tid >> 6;
    const int g = lane >> 4, rln = lane & 15;
    const int bid = blockIdx.x;             // 1024 blocks

    int rvec, cvec, rowTab, colTab;
    if (bid < 512) {        // G: data(rows) x rec(cols); 8b x 16rp x 4mh
        int b = bid >> 6, rp = (bid >> 2) & 15, mh = bid & 3;
        rvec = RV_BASE + (b * N8K + rp * 512) * 8;
        cvec = CR_BASE + (b * N2K + mh * 512) * 8;
        rowTab = D1_BASE + b * N8K + rp * 512;
        colTab = D2_BASE + b * N2K + mh * 512;
    } else {                // P: dataseg x recpseg; 32bp x 4rq x 4mh
        int j = bid - 512, bp = j >> 4, rq = (j >> 2) & 3, mh = j & 3;
        int b = bp >> 2, p = bp & 3;
        rvec = RV_BASE + (b * N8K + p * N2K + rq * 512) * 8;
        cvec = CP_BASE + (b * N8K + p * N2K + mh * 512) * 8;
        rowTab = P1_BASE + b * N8K + p * N2K + rq * 512;
        colTab = P2_BASE + b * N8K + p * N2K + mh * 512;
    }

    // stage 512 col-vecs into LDS (2 x uint4 per point, stride 12 u32)
    {
        const uint4* src = (const uint4*)(ws + cvec);
        for (int pt = tid; pt < 512; pt += THREADS) {
            uint4 w0 = src[pt * 2], w1 = src[pt * 2 + 1];
            unsigned int* dst = sB + pt * 12;
            *(uint4*)dst = w0;
            *(uint4*)(dst + 4) = w1;
        }
    }

    const char* base = (const char*)ws;
    const bf16x8 zero8 = {0, 0, 0, 0, 0, 0, 0, 0};
    const f32x4 zacc = {0.f, 0.f, 0.f, 0.f};

    // A-frags: 8 row-panels of 16; lane supplies A[row=rln][k=g*8+e]
    bf16x8 afr[8];
    #pragma unroll
    for (int p = 0; p < 8; ++p) {
        int row = wv * 128 + p * 16 + rln;
        afr[p] = (g < 2)
            ? *(const bf16x8*)(base + (size_t)(rvec + row * 8) * 4 + g * 16)
            : zero8;
    }
    float rm[8][4];
    #pragma unroll
    for (int p = 0; p < 8; ++p) {
        rm[p][0] = 3.4e38f; rm[p][1] = 3.4e38f;
        rm[p][2] = 3.4e38f; rm[p][3] = 3.4e38f;
    }

    __syncthreads();

    unsigned int* mins = ws;

    #pragma unroll 1
    for (int half = 0; half < 2; ++half) {
        float colm[16];   // static indices only (full unroll below)
        #pragma unroll
        for (int tt = 0; tt < 16; ++tt) {
            const int t = half * 16 + tt;
            bf16x8 bu = zero8;
            if (g < 2)
                bu = *(const bf16x8*)((const char*)sB + (t * 16 + rln) * 48 + g * 16);
            float cmt = 3.4e38f;
            #pragma unroll
            for (int p = 0; p < 8; ++p) {
                f32x4 d = __builtin_amdgcn_mfma_f32_16x16x32_bf16(afr[p], bu, zacc, 0, 0, 0);
                rm[p][0] = fminf(rm[p][0], d[0]);
                rm[p][1] = fminf(rm[p][1], d[1]);
                rm[p][2] = fminf(rm[p][2], d[2]);
                rm[p][3] = fminf(rm[p][3], d[3]);
                float w = min3f(d[1], d[2], d[3]);     // independent per p
                cmt = min3f(cmt, d[0], w);             // 8-deep chain
            }
            colm[tt] = cmt;
        }
        // batched cross-group reduction (16 independent shfl pairs), then
        // one atomic per column from lanes 0-15
        #pragma unroll
        for (int tt = 0; tt < 16; ++tt) {
            float v = colm[tt];
            v = fminf(v, __shfl_xor(v, 16, 64));
            v = fminf(v, __shfl_xor(v, 32, 64));
            if (lane < 16)
                atomicMin(&mins[colTab + (half * 16 + tt) * 16 + rln], fkey(v));
        }
    }

    // row-mins: reduce across 16 col-lanes (xor 1,2,4,8), one atomic per row
    #pragma unroll
    for (int p = 0; p < 8; ++p) {
        #pragma unroll
        for (int q = 0; q < 4; ++q) {
            float v = rm[p][q];
            v = fminf(v, __shfl_xor(v, 1, 64));
            v = fminf(v, __shfl_xor(v, 2, 64));
            v = fminf(v, __shfl_xor(v, 4, 64));
            v = fminf(v, __shfl_xor(v, 8, 64));
            if (rln == 0)
                atomicMin(&mins[rowTab + wv * 128 + p * 16 + g * 4 + q], fkey(v));
        }
    }
}

__global__ __launch_bounds__(THREADS) void finalize1_kernel(
    const unsigned int* __restrict__ mins, float* __restrict__ part)
{
    __shared__ float sred[4];
    const int blk = blockIdx.x;        // 208 blocks x 1024 entries
    const int tid = threadIdx.x;

    float s = 0.f;
    #pragma unroll
    for (int i = 0; i < 4; ++i) {
        int idx = blk * 1024 + i * THREADS + tid;
        unsigned int k = mins[idx];
        unsigned int bu = (k & 0x80000000u) ? (k & 0x7FFFFFFFu) : ~k;
        float v = __uint_as_float(bu);
        float w = (idx < 65536) ? (1.f / 65536.f) : (1.f / 16384.f);
        s += v * w;
    }
    #pragma unroll
    for (int o = 32; o > 0; o >>= 1) s += __shfl_down(s, o, 64);
    const int lane = tid & 63, wid = tid >> 6;
    if (lane == 0) sred[wid] = s;
    __syncthreads();
    if (tid == 0)
        part[blk] = (sred[0] + sred[1]) + (sred[2] + sred[3]);
}

__global__ __launch_bounds__(THREADS) void finalize2_kernel(
    const float* __restrict__ part, float* __restrict__ out)
{
    __shared__ float sred[4];
    const int tid = threadIdx.x;
    float s = (tid < 208) ? part[tid] : 0.f;
    #pragma unroll
    for (int o = 32; o > 0; o >>= 1) s += __shfl_down(s, o, 64);
    const int lane = tid & 63, wid = tid >> 6;
    if (lane == 0) sred[wid] = s;
    __syncthreads();
    if (tid == 0)
        out[0] = ((sred[0] + sred[1]) + (sred[2] + sred[3])) * 0.2f;  // /5
}

extern "C" void kernel_launch(void* const* d_in, const int* in_sizes, int n_in,
                              void* d_out, int out_size, void* d_ws, size_t ws_size,
                              hipStream_t stream) {
    const float* data = (const float*)d_in[0];
    const float* rec  = (const float*)d_in[1];
    const float* recp = (const float*)d_in[2];
    float* out = (float*)d_out;
    unsigned int* ws = (unsigned int*)d_ws;
    float* part = (float*)d_ws + PART_BASE;

    prep_kernel<<<576, THREADS, 0, stream>>>(data, rec, recp, ws);
    mfma_chamfer_kernel<<<1024, THREADS, 0, stream>>>(ws);
    finalize1_kernel<<<208, THREADS, 0, stream>>>(ws, part);
    finalize2_kernel<<<1, THREADS, 0, stream>>>(part, out);
}

// Round 14
// 47.690 us; speedup vs baseline: 3.8708x; 3.8708x over previous
//
#include <hip/hip_runtime.h>

// Chamfer via MFMA (math verified exact in R11/R12): d[n,m] = na + nb - 2 a.b
// as ONE bf16 MFMA (16x16x32) per 16x16 tile, 13-slot K packing w/ hi/lo:
//   k 0-2: ah*(-2bh)  k 3-5: ah*(-2bl)  k 6-8: al*(-2bh)
//   k 9,10: nah,nal * 1   k 11,12: 1 * nbh,nbl   k>=13: zero (g>=2 lanes)
// Each matrix computed ONCE: row-mins -> d1/p1, col-mins -> d2/p2.
// R14 schedule: t-loop has NO cross-lane ops and NO long-lived reg arrays.
// Per-lane col partial -> one ds_write_b32 into cT[wave][col][g] (16 KB);
// two halves of 16 t each; per-half merge (min over 16 slots) + 1 atomic
// per col. Row mins unchanged. LDS = 24 KB sB + 16 KB cT = 40 KB (4 blk/CU).
// atomicMin monotone-key table (exact, order-independent -> deterministic);
// min-table 0xFF init fused into prep.

#define N2K 2048
#define N8K 8192
#define THREADS 256

// ws u32 layout:
#define D1_BASE 0          // d1: b*8192+a
#define D2_BASE 65536      // d2: b*2048+a
#define P1_BASE 81920      // p1: b*8192+p*2048+a
#define P2_BASE 147456     // p2: b*8192+p*2048+a
#define NMINS 212992
#define PART_BASE 212992   // 208 floats
#define RV_BASE 213504     // data row-vecs : 65536 pts x 8 u32 (32B)
#define CR_BASE 737792     // rec  col-vecs : 16384 pts x 8 u32
#define CP_BASE 868864     // recp col-vecs : 65536 pts x 8 u32  (end 1393152)

typedef short bf16x8 __attribute__((ext_vector_type(8)));
typedef float f32x4 __attribute__((ext_vector_type(4)));

__device__ __forceinline__ float min3f(float a, float b, float c) {
    float d;
    asm("v_min3_f32 %0, %1, %2, %3" : "=v"(d) : "v"(a), "v"(b), "v"(c));
    return d;
}
__device__ __forceinline__ unsigned int fkey(float v) {
    unsigned int u = __float_as_uint(v);
    return (u & 0x80000000u) ? ~u : (u | 0x80000000u);
}
__device__ __forceinline__ unsigned short bf16rne(float f) {
    unsigned int u = __float_as_uint(f);
    return (unsigned short)((u + 0x7FFFu + ((u >> 16) & 1u)) >> 16);
}
__device__ __forceinline__ float bf2f(unsigned short s) {
    return __uint_as_float(((unsigned int)s) << 16);
}

__global__ __launch_bounds__(THREADS) void prep_kernel(
    const float* __restrict__ data, const float* __restrict__ rec,
    const float* __restrict__ recp, unsigned int* __restrict__ ws)
{
    const int idx = blockIdx.x * THREADS + threadIdx.x;   // 0..147455

    // fused min-table init (replaces hipMemsetAsync): [0, NMINS) <- 0xFF..
    if (idx < NMINS) ws[idx] = 0xFFFFFFFFu;
    if (idx + 147456 < NMINS) ws[idx + 147456] = 0xFFFFFFFFu;

    float x, y, z; int out; int isrow;
    if (idx < 65536) {                       // data -> row vectors
        int b = idx >> 13, i = idx & 8191;
        const float* p = data + b * 3 * N8K;
        x = p[i]; y = p[N8K + i]; z = p[2 * N8K + i];
        out = RV_BASE + idx * 8; isrow = 1;
    } else if (idx < 81920) {                // rec -> col vectors
        int j = idx - 65536; int b = j >> 11, i = j & 2047;
        const float* p = rec + b * 3 * N2K;
        x = p[i]; y = p[N2K + i]; z = p[2 * N2K + i];
        out = CR_BASE + j * 8; isrow = 0;
    } else {                                 // recp -> col vectors
        int j = idx - 81920; int b = j >> 13, i = j & 8191;
        const float* p = recp + b * 3 * N8K;
        x = p[i]; y = p[N8K + i]; z = p[2 * N8K + i];
        out = CP_BASE + j * 8; isrow = 0;
    }
    unsigned short xh = bf16rne(x), yh = bf16rne(y), zh = bf16rne(z);
    unsigned short xl = bf16rne(x - bf2f(xh));
    unsigned short yl = bf16rne(y - bf2f(yh));
    unsigned short zl = bf16rne(z - bf2f(zh));
    float na = x * x + y * y + z * z;
    unsigned short nh = bf16rne(na);
    unsigned short nl = bf16rne(na - bf2f(nh));
    const unsigned short ONE = 0x3F80u;
    unsigned short s[16];
    if (isrow) {
        s[0]=xh; s[1]=yh; s[2]=zh;  s[3]=xh; s[4]=yh; s[5]=zh;
        s[6]=xl; s[7]=yl; s[8]=zl;  s[9]=nh; s[10]=nl;
        s[11]=ONE; s[12]=ONE; s[13]=0; s[14]=0; s[15]=0;
    } else {
        unsigned short m2xh = bf16rne(-2.f * bf2f(xh));
        unsigned short m2yh = bf16rne(-2.f * bf2f(yh));
        unsigned short m2zh = bf16rne(-2.f * bf2f(zh));
        unsigned short m2xl = bf16rne(-2.f * bf2f(xl));
        unsigned short m2yl = bf16rne(-2.f * bf2f(yl));
        unsigned short m2zl = bf16rne(-2.f * bf2f(zl));
        s[0]=m2xh; s[1]=m2yh; s[2]=m2zh;  s[3]=m2xl; s[4]=m2yl; s[5]=m2zl;
        s[6]=m2xh; s[7]=m2yh; s[8]=m2zh;  s[9]=ONE; s[10]=ONE;
        s[11]=nh; s[12]=nl; s[13]=0; s[14]=0; s[15]=0;
    }
    uint4 w0, w1;
    w0.x = (unsigned)s[0]  | ((unsigned)s[1]  << 16);
    w0.y = (unsigned)s[2]  | ((unsigned)s[3]  << 16);
    w0.z = (unsigned)s[4]  | ((unsigned)s[5]  << 16);
    w0.w = (unsigned)s[6]  | ((unsigned)s[7]  << 16);
    w1.x = (unsigned)s[8]  | ((unsigned)s[9]  << 16);
    w1.y = (unsigned)s[10] | ((unsigned)s[11] << 16);
    w1.z = (unsigned)s[12] | ((unsigned)s[13] << 16);
    w1.w = (unsigned)s[14] | ((unsigned)s[15] << 16);
    uint4* dst = (uint4*)(ws + out);
    dst[0] = w0; dst[1] = w1;
}

__global__ __launch_bounds__(THREADS) void mfma_chamfer_kernel(unsigned int* ws)
{
    __shared__ unsigned int sB[512 * 12];   // col-vecs, 48B stride (24 KB)
    __shared__ float cT[4][256][4];         // [wave][col_local][g] (16 KB)

    const int tid = threadIdx.x, lane = tid & 63, wv = tid >> 6;
    const int g = lane >> 4, rln = lane & 15;
    const int bid = blockIdx.x;             // 1024 blocks

    int rvec, cvec, rowTab, colTab;
    if (bid < 512) {        // G: data(rows) x rec(cols); 8b x 16rp x 4mh
        int b = bid >> 6, rp = (bid >> 2) & 15, mh = bid & 3;
        rvec = RV_BASE + (b * N8K + rp * 512) * 8;
        cvec = CR_BASE + (b * N2K + mh * 512) * 8;
        rowTab = D1_BASE + b * N8K + rp * 512;
        colTab = D2_BASE + b * N2K + mh * 512;
    } else {                // P: dataseg x recpseg; 32bp x 4rq x 4mh
        int j = bid - 512, bp = j >> 4, rq = (j >> 2) & 3, mh = j & 3;
        int b = bp >> 2, p = bp & 3;
        rvec = RV_BASE + (b * N8K + p * N2K + rq * 512) * 8;
        cvec = CP_BASE + (b * N8K + p * N2K + mh * 512) * 8;
        rowTab = P1_BASE + b * N8K + p * N2K + rq * 512;
        colTab = P2_BASE + b * N8K + p * N2K + mh * 512;
    }

    // stage 512 col-vecs into LDS (2 x uint4 per point, stride 12 u32)
    {
        const uint4* src = (const uint4*)(ws + cvec);
        for (int pt = tid; pt < 512; pt += THREADS) {
            uint4 w0 = src[pt * 2], w1 = src[pt * 2 + 1];
            unsigned int* dst = sB + pt * 12;
            *(uint4*)dst = w0;
            *(uint4*)(dst + 4) = w1;
        }
    }

    const char* base = (const char*)ws;
    const bf16x8 zero8 = {0, 0, 0, 0, 0, 0, 0, 0};
    const f32x4 zacc = {0.f, 0.f, 0.f, 0.f};

    // A-frags: 8 row-panels of 16; lane supplies A[row=rln][k=g*8+e]
    bf16x8 afr[8];
    #pragma unroll
    for (int p = 0; p < 8; ++p) {
        int row = wv * 128 + p * 16 + rln;
        afr[p] = (g < 2)
            ? *(const bf16x8*)(base + (size_t)(rvec + row * 8) * 4 + g * 16)
            : zero8;
    }
    float rm[8][4];
    #pragma unroll
    for (int p = 0; p < 8; ++p) {
        rm[p][0] = 3.4e38f; rm[p][1] = 3.4e38f;
        rm[p][2] = 3.4e38f; rm[p][3] = 3.4e38f;
    }

    __syncthreads();

    unsigned int* mins = ws;

    #pragma unroll 1
    for (int half = 0; half < 2; ++half) {
        #pragma unroll 2
        for (int tt = 0; tt < 16; ++tt) {
            const int t = half * 16 + tt;
            bf16x8 bu = zero8;
            if (g < 2)
                bu = *(const bf16x8*)((const char*)sB + (t * 16 + rln) * 48 + g * 16);
            f32x4 d[8];
            #pragma unroll
            for (int p = 0; p < 8; ++p)
                d[p] = __builtin_amdgcn_mfma_f32_16x16x32_bf16(afr[p], bu, zacc, 0, 0, 0);
            float cmt = 3.4e38f;
            #pragma unroll
            for (int p = 0; p < 8; ++p) {
                rm[p][0] = fminf(rm[p][0], d[p][0]);
                rm[p][1] = fminf(rm[p][1], d[p][1]);
                rm[p][2] = fminf(rm[p][2], d[p][2]);
                rm[p][3] = fminf(rm[p][3], d[p][3]);
                float w = min3f(d[p][1], d[p][2], d[p][3]);   // indep per p
                cmt = min3f(cmt, d[p][0], w);                 // 8-deep chain
            }
            cT[wv][tt * 16 + rln][g] = cmt;    // unique slot, no conflicts
        }
        __syncthreads();
        // merge: 256 threads x 256 local cols; min over 4 waves x 4 g
        {
            float4 q0 = *(const float4*)&cT[0][tid][0];
            float4 q1 = *(const float4*)&cT[1][tid][0];
            float4 q2 = *(const float4*)&cT[2][tid][0];
            float4 q3 = *(const float4*)&cT[3][tid][0];
            float v = fminf(fminf(fminf(q0.x, q0.y), fminf(q0.z, q0.w)),
                            fminf(fminf(q1.x, q1.y), fminf(q1.z, q1.w)));
            v = fminf(v, fminf(fminf(q2.x, q2.y), fminf(q2.z, q2.w)));
            v = fminf(v, fminf(fminf(q3.x, q3.y), fminf(q3.z, q3.w)));
            atomicMin(&mins[colTab + half * 256 + tid], fkey(v));
        }
        __syncthreads();
    }

    // row-mins: reduce across 16 col-lanes (xor 1,2,4,8), one atomic per row
    #pragma unroll
    for (int p = 0; p < 8; ++p) {
        #pragma unroll
        for (int q = 0; q < 4; ++q) {
            float v = rm[p][q];
            v = fminf(v, __shfl_xor(v, 1, 64));
            v = fminf(v, __shfl_xor(v, 2, 64));
            v = fminf(v, __shfl_xor(v, 4, 64));
            v = fminf(v, __shfl_xor(v, 8, 64));
            if (rln == 0)
                atomicMin(&mins[rowTab + wv * 128 + p * 16 + g * 4 + q], fkey(v));
        }
    }
}

__global__ __launch_bounds__(THREADS) void finalize1_kernel(
    const unsigned int* __restrict__ mins, float* __restrict__ part)
{
    __shared__ float sred[4];
    const int blk = blockIdx.x;        // 208 blocks x 1024 entries
    const int tid = threadIdx.x;

    float s = 0.f;
    #pragma unroll
    for (int i = 0; i < 4; ++i) {
        int idx = blk * 1024 + i * THREADS + tid;
        unsigned int k = mins[idx];
        unsigned int bu = (k & 0x80000000u) ? (k & 0x7FFFFFFFu) : ~k;
        float v = __uint_as_float(bu);
        float w = (idx < 65536) ? (1.f / 65536.f) : (1.f / 16384.f);
        s += v * w;
    }
    #pragma unroll
    for (int o = 32; o > 0; o >>= 1) s += __shfl_down(s, o, 64);
    const int lane = tid & 63, wid = tid >> 6;
    if (lane == 0) sred[wid] = s;
    __syncthreads();
    if (tid == 0)
        part[blk] = (sred[0] + sred[1]) + (sred[2] + sred[3]);
}

__global__ __launch_bounds__(THREADS) void finalize2_kernel(
    const float* __restrict__ part, float* __restrict__ out)
{
    __shared__ float sred[4];
    const int tid = threadIdx.x;
    float s = (tid < 208) ? part[tid] : 0.f;
    #pragma unroll
    for (int o = 32; o > 0; o >>= 1) s += __shfl_down(s, o, 64);
    const int lane = tid & 63, wid = tid >> 6;
    if (lane == 0) sred[wid] = s;
    __syncthreads();
    if (tid == 0)
        out[0] = ((sred[0] + sred[1]) + (sred[2] + sred[3])) * 0.2f;  // /5
}

extern "C" void kernel_launch(void* const* d_in, const int* in_sizes, int n_in,
                              void* d_out, int out_size, void* d_ws, size_t ws_size,
                              hipStream_t stream) {
    const float* data = (const float*)d_in[0];
    const float* rec  = (const float*)d_in[1];
    const float* recp = (const float*)d_in[2];
    float* out = (float*)d_out;
    unsigned int* ws = (unsigned int*)d_ws;
    float* part = (float*)d_ws + PART_BASE;

    prep_kernel<<<576, THREADS, 0, stream>>>(data, rec, recp, ws);
    mfma_chamfer_kernel<<<1024, THREADS, 0, stream>>>(ws);
    finalize1_kernel<<<208, THREADS, 0, stream>>>(ws, part);
    finalize2_kernel<<<1, THREADS, 0, stream>>>(part, out);
}